// Round 10
// baseline (223.293 us; speedup 1.0000x reference)
//
#include <hip/hip_runtime.h>

// CGP coupler, all-LDS flat-stream scatter form — native ds_add_f32 edition.
//
// Structure (validated on-device R3-R8): entries come in runs of 32 with
// consecutive r1/r2/ro, constant cg, 32-aligned bases, a,b < 1024, ob < 280:
//   out[:, 32*ob : 32*ob+32] += cg_s * x1[:, a:a+32] * x2[:, b:b+32]
// over nseg = K/32 segments (~560).
//
// R8 lesson: atomicAdd(float*) on LDS compiles to a CAS loop (safe-fp-atomics
// default; ds_add_f32 flushes denormals so the compiler won't emit it
// unprompted) — ~400+ cy serial RMW per add; every LDS-atomic variant
// (R1/R7/R8) sat at ~200 µs independent of iteration count. Fix: HIP's
// documented unsafeAtomicAdd, which emits fire-and-forget ds_add_f32 for
// shared pointers (R9's raw builtin failed host-pass type-check).
// Everything else unchanged from R8:
//   - x1 row, x2 row, descriptor array staged in LDS once per block
//   - inner loop: uniform ds_read desc -> 2-way-aliased ds_read x1s/x2s
//     (free per m136) -> mul -> ds_add_f32 (no return, no dependence)
//   - 512 thr/block, 48.6 KB LDS -> 3 blocks/CU, ~18 iterations/thread.
//
// Descriptor pack: x = a | b<<10 | ob<<20, y = cg bits. Pads have cg=0,
// a=b=ob=0 -> harmless +0.0 into outs[0..31].

#define IN_DIM 1024

__device__ __forceinline__ void lds_fadd(float* p, float v) {
    unsafeAtomicAdd(p, v);      // shared ptr -> ds_add_f32 (no CAS, no return use)
}

__global__ void seg_extract(const int* __restrict__ r1, const int* __restrict__ r2,
                            const int* __restrict__ ro, const float* __restrict__ cg,
                            int nseg, int nsegPad, uint2* __restrict__ seg)
{
    int s = blockIdx.x * blockDim.x + threadIdx.x;
    if (s >= nsegPad) return;
    uint2 d;
    if (s < nseg) {
        int k = s << 5;                       // first entry of the 32-run
        d.x = (unsigned int)r1[k]
            | ((unsigned int)r2[k] << 10)
            | ((unsigned int)(ro[k] >> 5) << 20);
        d.y = __float_as_uint(cg[k]);
    } else {
        d.x = 0u;
        d.y = 0u;
    }
    seg[s] = d;
}

__global__ __launch_bounds__(512) void cgp_main(const float* __restrict__ x1,
                                                const float* __restrict__ x2,
                                                const uint2* __restrict__ seg,
                                                float* __restrict__ out,
                                                int out_dim, int steps)
{
    extern __shared__ float lds[];
    float* outs = lds;                          // out_dim (8960)
    float* x1s  = lds + out_dim;                // 1024
    float* x2s  = x1s + IN_DIM;                 // 1024
    uint2* dsc  = (uint2*)(x2s + IN_DIM);       // steps*32

    const int row = blockIdx.x;
    const int tid = threadIdx.x;                // 0..511

    // ---- prologue: zero accumulator, stage rows + descriptors ----
    {
        float4* o4 = reinterpret_cast<float4*>(outs);
        const int nv = out_dim >> 2;            // 2240
        for (int j = tid; j < nv; j += 512)
            o4[j] = make_float4(0.f, 0.f, 0.f, 0.f);

        const float4* p1 = reinterpret_cast<const float4*>(x1 + (size_t)row * IN_DIM);
        const float4* p2 = reinterpret_cast<const float4*>(x2 + (size_t)row * IN_DIM);
        float4* s1 = reinterpret_cast<float4*>(x1s);
        float4* s2 = reinterpret_cast<float4*>(x2s);
        if (tid < (IN_DIM >> 2)) {              // 256 threads: one float4 each
            s1[tid] = p1[tid];
            s2[tid] = p2[tid];
        }
        const int ndesc = steps << 5;           // steps*32
        for (int j = tid; j < ndesc; j += 512)
            dsc[j] = seg[j];
    }
    __syncthreads();

    // ---- main: pure-LDS flat walk, 32 segments/step, 2 per thread-slot ----
    const int slot = tid >> 5;                  // 0..15 (wave*2 + half)
    const int t    = tid & 31;                  // channel within the 32-run

    #pragma unroll 2
    for (int i = 0; i < steps; ++i) {
        const uint2 d0 = dsc[(i << 5) + slot];        // uniform per half-wave
        const uint2 d1 = dsc[(i << 5) + 16 + slot];
        const int a0 = (int)(d0.x & 1023u);
        const int b0 = (int)((d0.x >> 10) & 1023u);
        const int o0 = (int)(d0.x >> 20);
        const int a1 = (int)(d1.x & 1023u);
        const int b1 = (int)((d1.x >> 10) & 1023u);
        const int o1 = (int)(d1.x >> 20);
        const float v0 = __uint_as_float(d0.y) * x1s[a0 + t] * x2s[b0 + t];
        const float v1 = __uint_as_float(d1.y) * x1s[a1 + t] * x2s[b1 + t];
        lds_fadd(&outs[(o0 << 5) + t], v0);     // native ds_add_f32
        lds_fadd(&outs[(o1 << 5) + t], v1);
    }
    __syncthreads();

    // ---- epilogue: flush the row (coalesced float4 stores) ----
    {
        const float4* o4 = reinterpret_cast<const float4*>(outs);
        float4* og = reinterpret_cast<float4*>(out + (size_t)row * out_dim);
        const int nv = out_dim >> 2;
        for (int j = tid; j < nv; j += 512)
            og[j] = o4[j];
    }
}

extern "C" void kernel_launch(void* const* d_in, const int* in_sizes, int n_in,
                              void* d_out, int out_size, void* d_ws, size_t ws_size,
                              hipStream_t stream)
{
    const float* x1 = (const float*)d_in[0];
    const float* x2 = (const float*)d_in[1];
    const float* cg = (const float*)d_in[2];
    const int*   r1 = (const int*)d_in[3];
    const int*   r2 = (const int*)d_in[4];
    const int*   ro = (const int*)d_in[5];
    float* out = (float*)d_out;

    const int B       = in_sizes[0] / IN_DIM;  // 2048
    const int out_dim = out_size / B;          // 8960
    const int K       = in_sizes[2];
    const int nseg    = K >> 5;                // all degs are 32 (~560)
    const int steps   = (nseg + 31) >> 5;      // 32 segments per step
    const int nsegPad = steps << 5;

    uint2* seg = (uint2*)d_ws;                 // nsegPad * 8 B (~4.6 KB)

    {
        int blk = 256, grd = (nsegPad + blk - 1) / blk;
        hipLaunchKernelGGL(seg_extract, dim3(grd), dim3(blk), 0, stream,
                           r1, r2, ro, cg, nseg, nsegPad, seg);
    }
    {
        const size_t lds_bytes = (size_t)out_dim * sizeof(float)     // 35840
                               + 2 * IN_DIM * sizeof(float)          // 8192
                               + (size_t)nsegPad * sizeof(uint2);    // 4608
        hipLaunchKernelGGL(cgp_main, dim3(B), dim3(512), lds_bytes, stream,
                           x1, x2, seg, out, out_dim, steps);
    }
}

// Round 11
// 61.071 us; speedup vs baseline: 3.6563x; 3.6563x over previous
//
#include <hip/hip_runtime.h>

// CGP coupler, sorted-flat-walk register-accumulation form.
//
// Structure (validated on-device R3-R10): entries come in runs of 32 with
// consecutive r1/r2/ro, constant cg, 32-aligned bases, a,b < 1024, ob < 280:
//   out[:, 32*ob : 32*ob+32] += cg_s * x1[:, a:a+32] * x2[:, b:b+32]
// over nseg = K/32 segments (~560), avg ~2 segments per ob.
//
// Ten-round empirical law:
//   - LDS-scatter loops (atomic or not): ~200+ us — the LDS write aliases
//     the LDS reads (one extern-shared block), killing all load hoisting
//     (VGPR=8 every time).
//   - short dynamic per-ob loops: ~50 us — serial off[]->csr[]->gather
//     chains, ~1000 cy per ob, no pipelining across obs.
// This kernel uses the unexplored quadrant: ONE long flat loop per wave
// over a CONTIGUOUS slice of the ob-sorted segment stream; LDS is
// READ-ONLY in the loop; descriptors are wave-uniform monotone s_loads;
// accumulator in a register; store to global at (wave-uniform) ob
// transitions. No atomics anywhere in the main kernel.

#define NOB_MAX 512

// ---- pass 1: histogram output blocks ----
__global__ void seg_count(const int* __restrict__ ro, int nseg,
                          int* __restrict__ cnt)
{
    int s = blockIdx.x * blockDim.x + threadIdx.x;
    if (s >= nseg) return;
    atomicAdd(&cnt[ro[s << 5] >> 5], 1);
}

// ---- pass 2: exclusive scan of per-ob counts ----
__global__ __launch_bounds__(512) void scan_kernel(const int* __restrict__ cnt,
                                                   int* __restrict__ off, int nob)
{
    __shared__ int buf[512];
    int t = threadIdx.x;
    buf[t] = (t < nob) ? cnt[t] : 0;
    __syncthreads();
    for (int d = 1; d < 512; d <<= 1) {
        int v = (t >= d) ? buf[t - d] : 0;
        __syncthreads();
        buf[t] += v;
        __syncthreads();
    }
    if (t < nob) off[t + 1] = buf[t];
    if (t == 0) off[0] = 0;
}

// ---- pass 3: counting-sort fill; desc pack x = a | b<<10 | ob<<20, y = cg.
//      Order within an ob is arbitrary (fp reorder noise ~1e-5 << 0.29). ----
__global__ void csr_fill(const int* __restrict__ r1, const int* __restrict__ r2,
                         const int* __restrict__ ro, const float* __restrict__ cg,
                         const int* __restrict__ off, int* __restrict__ rank,
                         int nseg, uint2* __restrict__ csr)
{
    int s = blockIdx.x * blockDim.x + threadIdx.x;
    if (s >= nseg) return;
    int k = s << 5;
    int ob = ro[k] >> 5;
    int pos = off[ob] + atomicAdd(&rank[ob], 1);
    uint2 d;
    d.x = (unsigned int)r1[k]
        | ((unsigned int)r2[k] << 10)
        | ((unsigned int)ob << 20);
    d.y = __float_as_uint(cg[k]);
    csr[pos] = d;
}

// ---- main: block = 2 rows; 4 waves each walk a contiguous quarter of the
//      sorted stream. lane = half*32 + t, half = row, t = channel. ----
__global__ __launch_bounds__(256) void cgp_main(const float* __restrict__ x1,
                                                const float* __restrict__ x2,
                                                const uint2* __restrict__ csr,
                                                const int* __restrict__ off,
                                                float* __restrict__ out,
                                                int out_dim, int nob)
{
    __shared__ float x1s[2 * 1024];
    __shared__ float x2s[2 * 1024];

    const int b0  = blockIdx.x << 1;
    const int tid = threadIdx.x;

    // ---- stage 2 contiguous rows of each input (read-only thereafter) ----
    {
        const float4* p1 = reinterpret_cast<const float4*>(x1 + (size_t)b0 * 1024);
        const float4* p2 = reinterpret_cast<const float4*>(x2 + (size_t)b0 * 1024);
        float4* s1 = reinterpret_cast<float4*>(x1s);
        float4* s2 = reinterpret_cast<float4*>(x2s);
        for (int j = tid; j < 512; j += 256) {   // 2 rows * 1024 f = 512 f4
            s1[j] = p1[j];
            s2[j] = p2[j];
        }
    }
    __syncthreads();

    const int wid  = tid >> 6;               // 0..3
    const int lane = tid & 63;
    const int half = lane >> 5;              // row within the pair
    const int t    = lane & 31;              // channel within the 32-block

    const float* __restrict__ xs1 = x1s + (half << 10);
    const float* __restrict__ xs2 = x2s + (half << 10);
    float* __restrict__ orow = out + (size_t)(b0 + half) * out_dim + t;

    const int opw  = (nob + 3) >> 2;         // obs per wave (70)
    const int obLo = wid * opw;
    const int obHi = (obLo + opw < nob) ? obLo + opw : nob;

    // ---- zero-fill empty obs (d_out is poisoned, not zeroed) ----
    for (int ob = obLo; ob < obHi; ++ob)
        if (off[ob + 1] == off[ob])
            orow[ob << 5] = 0.0f;

    // ---- flat walk over this wave's contiguous sorted slice ----
    const int s0  = off[obLo];               // wave-uniform
    const int s1e = off[obHi];
    float acc = 0.0f;
    int   cur = -1;
    for (int s = s0; s < s1e; ++s) {
        const uint2 d = csr[s];              // uniform monotone -> s_load
        const int ob = (int)(d.x >> 20);
        if (ob != cur) {                     // wave-uniform scalar branch
            if (cur >= 0) orow[cur << 5] = acc;
            acc = 0.0f;
            cur = ob;
        }
        const int a = (int)(d.x & 1023u);
        const int b = (int)((d.x >> 10) & 1023u);
        acc = fmaf(__uint_as_float(d.y), xs1[a + t] * xs2[b + t], acc);
    }
    if (cur >= 0) orow[cur << 5] = acc;
}

extern "C" void kernel_launch(void* const* d_in, const int* in_sizes, int n_in,
                              void* d_out, int out_size, void* d_ws, size_t ws_size,
                              hipStream_t stream)
{
    const float* x1 = (const float*)d_in[0];
    const float* x2 = (const float*)d_in[1];
    const float* cg = (const float*)d_in[2];
    const int*   r1 = (const int*)d_in[3];
    const int*   r2 = (const int*)d_in[4];
    const int*   ro = (const int*)d_in[5];
    float* out = (float*)d_out;

    const int in_dim  = 1024;                  // fixed by METADATA
    const int B       = in_sizes[0] / in_dim;  // 2048
    const int out_dim = out_size / B;          // 8960
    const int K       = in_sizes[2];
    const int nseg    = K >> 5;                // all degs are 32
    const int nob     = out_dim >> 5;          // 280

    // ---- workspace layout (16B-aligned carving) ----
    auto align16 = [](size_t v) { return (v + 15) & ~(size_t)15; };
    char* ws = (char*)d_ws;
    uint2* csrD = (uint2*)ws;  ws += align16((size_t)nseg * sizeof(uint2));
    int*   cnt  = (int*)ws;    ws += align16((size_t)NOB_MAX * sizeof(int));
    int*   rank = (int*)ws;    ws += align16((size_t)NOB_MAX * sizeof(int));
    int*   off  = (int*)ws;

    hipMemsetAsync(cnt, 0, 2 * NOB_MAX * sizeof(int), stream);   // cnt AND rank

    {
        int blk = 256, grd = (nseg + blk - 1) / blk;
        hipLaunchKernelGGL(seg_count, dim3(grd), dim3(blk), 0, stream, ro, nseg, cnt);
    }
    hipLaunchKernelGGL(scan_kernel, dim3(1), dim3(512), 0, stream, cnt, off, nob);
    {
        int blk = 256, grd = (nseg + blk - 1) / blk;
        hipLaunchKernelGGL(csr_fill, dim3(grd), dim3(blk), 0, stream,
                           r1, r2, ro, cg, off, rank, nseg, csrD);
    }
    hipLaunchKernelGGL(cgp_main, dim3(B >> 1), dim3(256), 0, stream,
                       x1, x2, csrD, off, out, out_dim, nob);
}

// Round 12
// 37.859 us; speedup vs baseline: 5.8980x; 1.6131x over previous
//
#include <hip/hip_runtime.h>

// CGP coupler, padded-quad mixed store/atomic form.
//
// Structure (validated R3-R11): runs of 32 entries = segments
//   out[:, 32*ob:32*ob+32] += cg * x1[:, a:a+32] * x2[:, b:b+32]
// nseg ~ 580, nob = 280, avg ~2 segs per ob, a,b 32-aligned, < 1024.
//
// 11-round lesson: thin per-segment loop bodies never pipeline (VGPR=8-12
// every round; LDS-scatter aliasing and dynamic/branchy trip counts both
// poison the scheduler) -> every variant lands at 48-50 us or 200+ us.
// This design makes each iteration FAT and SELF-CONTAINED:
//   - each ob padded to a multiple of 4 segments ("quads", cg=0 pads)
//   - one wave-iteration = one quad: 32 B descriptor burst (scalar load),
//     8 independent ds_read_b64 (4 rows x 16 float2 lanes), FMA tree,
//     then ONE terminal output op:
//       * obs with <=4 segs (exclusive, majority): plain float2 store
//       * obs with  >4 segs (shared): pre-zeroed + native global fadd
//   - no loop-carried deps, no data-dependent branches (quad flag is
//     wave-uniform), fixed per-wave trip count from a device header.

#define IN_DIM 1024
#define ROWS   4
#define NOBCAP 512

// ---- A: per-ob segment histogram ----
__global__ void seg_count(const int* __restrict__ ro, int nseg, int* __restrict__ cnt)
{
    int s = blockIdx.x * blockDim.x + threadIdx.x;
    if (s < nseg) atomicAdd(&cnt[ro[s << 5] >> 5], 1);
}

// ---- B: plan (1 block): quad offsets, flags, shared-ob list, pad descs ----
__global__ __launch_bounds__(512) void plan_kernel(const int* __restrict__ cnt, int nob,
    int* __restrict__ qoff, unsigned int* __restrict__ flags, int* __restrict__ zlist,
    int* __restrict__ hdr, uint2* __restrict__ qdesc)
{
    __shared__ int bufQ[512], bufZ[512];
    const int t = threadIdx.x;
    const int c  = (t < nob) ? cnt[t] : 0;
    const int q  = (t < nob) ? (((c > 0 ? c : 1) + 3) >> 2) : 0;  // quads (empty ob -> 1)
    const int sh = (t < nob && c > 4) ? 1 : 0;                    // shared flag
    bufQ[t] = q; bufZ[t] = sh;
    __syncthreads();
    for (int d = 1; d < 512; d <<= 1) {
        int vq = (t >= d) ? bufQ[t - d] : 0;
        int vz = (t >= d) ? bufZ[t - d] : 0;
        __syncthreads();
        bufQ[t] += vq; bufZ[t] += vz;
        __syncthreads();
    }
    if (t < nob) {
        const int qb = bufQ[t] - q;                 // exclusive scan
        qoff[t] = qb;
        const unsigned int fl = sh ? 0u : 0x80000000u;   // bit31 = exclusive
        flags[t] = fl;
        if (sh) zlist[bufZ[t] - 1] = t;
        const unsigned int pd = ((unsigned int)t << 20) | fl;   // pad: a=b=0, cg=0
        for (int j = (qb << 2) + c; j < ((qb + q) << 2); ++j)
            qdesc[j] = make_uint2(pd, 0u);
    }
    __syncthreads();
    if (t == 0) {
        const int tot    = bufQ[nob - 1];
        const int totPad = (tot + 7) & ~7;          // pad quad count to 8
        for (int j = (tot << 2); j < (totPad << 2); ++j)
            qdesc[j] = make_uint2(0u, 0u);          // dummy: shared-path +0.0 to ob0
        hdr[0] = totPad;
        hdr[1] = bufZ[nob - 1];                     // number of shared obs
    }
}

// ---- C: fill real descriptors into their ob's quad slots ----
__global__ void quad_fill(const int* __restrict__ r1, const int* __restrict__ r2,
    const int* __restrict__ ro, const float* __restrict__ cg,
    const int* __restrict__ qoff, const unsigned int* __restrict__ flags,
    int* __restrict__ rank, int nseg, uint2* __restrict__ qdesc)
{
    int s = blockIdx.x * blockDim.x + threadIdx.x;
    if (s >= nseg) return;
    int k  = s << 5;
    int ob = ro[k] >> 5;
    int slot = (qoff[ob] << 2) + atomicAdd(&rank[ob], 1);
    qdesc[slot] = make_uint2((unsigned int)r1[k] | ((unsigned int)r2[k] << 10)
                             | ((unsigned int)ob << 20) | flags[ob],
                             __float_as_uint(cg[k]));
}

// ---- main: block = 4 rows, 8 waves; wave-iteration = one quad ----
__global__ __launch_bounds__(512) void cgp_main(const float* __restrict__ x1,
    const float* __restrict__ x2, const uint2* __restrict__ qdesc,
    const int* __restrict__ zlist, const int* __restrict__ hdr,
    float* __restrict__ out, int out_dim)
{
    __shared__ float x1s[ROWS * IN_DIM];
    __shared__ float x2s[ROWS * IN_DIM];
    const int r0  = blockIdx.x * ROWS;
    const int tid = threadIdx.x;

    // stage 4 rows of each input (read-only afterwards)
    {
        const float4* p1 = reinterpret_cast<const float4*>(x1 + (size_t)r0 * IN_DIM);
        const float4* p2 = reinterpret_cast<const float4*>(x2 + (size_t)r0 * IN_DIM);
        float4* s1 = reinterpret_cast<float4*>(x1s);
        float4* s2 = reinterpret_cast<float4*>(x2s);
        for (int j = tid; j < (ROWS * IN_DIM) >> 2; j += 512) { s1[j] = p1[j]; s2[j] = p2[j]; }
    }
    // zero only the shared obs of our 4 rows (exclusive obs are pure stores)
    const int nz = hdr[1];
    for (int i = tid; i < (nz << 5); i += 512) {
        const int ob = zlist[i >> 5];
        const int ch = i & 31;
        float* p = out + (size_t)r0 * out_dim + (ob << 5) + ch;
        p[0] = 0.f; p[out_dim] = 0.f; p[2 * out_dim] = 0.f; p[3 * out_dim] = 0.f;
    }
    __syncthreads();

    const int w  = tid >> 6;            // wave 0..7
    const int ln = tid & 63;
    const int rr = ln >> 4;             // row 0..3
    const int tt = ln & 15;             // float2-channel 0..15
    const float* xs1 = x1s + rr * IN_DIM + (tt << 1);
    const float* xs2 = x2s + rr * IN_DIM + (tt << 1);
    float* orow = out + (size_t)(r0 + rr) * out_dim + (tt << 1);

    const int nquads = hdr[0];          // multiple of 8
    const int qpw    = nquads >> 3;     // quads per wave
    const uint2* qd  = qdesc + ((size_t)(w * qpw) << 2);

    #pragma unroll 2
    for (int i = 0; i < qpw; ++i, qd += 4) {
        const uint4 A  = *reinterpret_cast<const uint4*>(qd);      // descs 0,1
        const uint4 Bq = *reinterpret_cast<const uint4*>(qd + 2);  // descs 2,3
        float sx = 0.f, sy = 0.f;
        {
            const float c = __uint_as_float(A.y);
            const float2 u = *reinterpret_cast<const float2*>(xs1 + (A.x & 1023u));
            const float2 v = *reinterpret_cast<const float2*>(xs2 + ((A.x >> 10) & 1023u));
            sx = fmaf(c, u.x * v.x, sx); sy = fmaf(c, u.y * v.y, sy);
        }
        {
            const float c = __uint_as_float(A.w);
            const float2 u = *reinterpret_cast<const float2*>(xs1 + (A.z & 1023u));
            const float2 v = *reinterpret_cast<const float2*>(xs2 + ((A.z >> 10) & 1023u));
            sx = fmaf(c, u.x * v.x, sx); sy = fmaf(c, u.y * v.y, sy);
        }
        {
            const float c = __uint_as_float(Bq.y);
            const float2 u = *reinterpret_cast<const float2*>(xs1 + (Bq.x & 1023u));
            const float2 v = *reinterpret_cast<const float2*>(xs2 + ((Bq.x >> 10) & 1023u));
            sx = fmaf(c, u.x * v.x, sx); sy = fmaf(c, u.y * v.y, sy);
        }
        {
            const float c = __uint_as_float(Bq.w);
            const float2 u = *reinterpret_cast<const float2*>(xs1 + (Bq.z & 1023u));
            const float2 v = *reinterpret_cast<const float2*>(xs2 + ((Bq.z >> 10) & 1023u));
            sx = fmaf(c, u.x * v.x, sx); sy = fmaf(c, u.y * v.y, sy);
        }
        float* p = orow + (((A.x >> 20) & 511u) << 5);
        if (A.x >> 31) {                               // exclusive ob: plain store
            *reinterpret_cast<float2*>(p) = make_float2(sx, sy);
        } else {                                       // shared ob: native fadd
            unsafeAtomicAdd(p, sx);
            unsafeAtomicAdd(p + 1, sy);
        }
    }
}

extern "C" void kernel_launch(void* const* d_in, const int* in_sizes, int n_in,
                              void* d_out, int out_size, void* d_ws, size_t ws_size,
                              hipStream_t stream)
{
    const float* x1 = (const float*)d_in[0];
    const float* x2 = (const float*)d_in[1];
    const float* cg = (const float*)d_in[2];
    const int*   r1 = (const int*)d_in[3];
    const int*   r2 = (const int*)d_in[4];
    const int*   ro = (const int*)d_in[5];
    float* out = (float*)d_out;

    const int B       = in_sizes[0] / IN_DIM;   // 2048
    const int out_dim = out_size / B;           // 8960
    const int K       = in_sizes[2];
    const int nseg    = K >> 5;                 // ~580
    const int nob     = out_dim >> 5;           // 280
    const int qcap    = nob + (nseg >> 2) + 16; // quad capacity upper bound

    auto align16 = [](size_t v) { return (v + 15) & ~(size_t)15; };
    char* ws = (char*)d_ws;
    uint2*        qdesc = (uint2*)ws;        ws += align16((size_t)qcap * 4 * sizeof(uint2));
    int*          cnt   = (int*)ws;          ws += align16((size_t)NOBCAP * sizeof(int));
    int*          rank  = (int*)ws;          ws += align16((size_t)NOBCAP * sizeof(int));
    int*          qoff  = (int*)ws;          ws += align16((size_t)NOBCAP * sizeof(int));
    unsigned int* flags = (unsigned int*)ws; ws += align16((size_t)NOBCAP * sizeof(int));
    int*          zlist = (int*)ws;          ws += align16((size_t)NOBCAP * sizeof(int));
    int*          hdr   = (int*)ws;

    hipMemsetAsync(cnt, 0, 2 * NOBCAP * sizeof(int), stream);   // cnt AND rank

    {
        int blk = 256, grd = (nseg + blk - 1) / blk;
        hipLaunchKernelGGL(seg_count, dim3(grd), dim3(blk), 0, stream, ro, nseg, cnt);
    }
    hipLaunchKernelGGL(plan_kernel, dim3(1), dim3(512), 0, stream,
                       cnt, nob, qoff, flags, zlist, hdr, qdesc);
    {
        int blk = 256, grd = (nseg + blk - 1) / blk;
        hipLaunchKernelGGL(quad_fill, dim3(grd), dim3(blk), 0, stream,
                           r1, r2, ro, cg, qoff, flags, rank, nseg, qdesc);
    }
    hipLaunchKernelGGL(cgp_main, dim3(B / ROWS), dim3(512), 0, stream,
                       x1, x2, qdesc, zlist, hdr, out, out_dim);
}

// Round 13
// 32.396 us; speedup vs baseline: 6.8925x; 1.1686x over previous
//
#include <hip/hip_runtime.h>

// CGP coupler, padded-quad form, single-dispatch preprocessing.
//
// Structure (validated R3-R12): runs of 32 entries = segments
//   out[:, 32*ob:32*ob+32] += cg * x1[:, a:a+32] * x2[:, b:b+32]
// nseg ~ 580, nob = 280, avg ~2 segs per ob, a,b 32-aligned, < 1024.
//
// R12 result: fat self-contained quad iterations finally pipeline ->
// 37.9 us total, and the profile shows preprocessing DISPATCHES (memset +
// 3 tiny kernels) are now the dominant overhead. Fix: fuse all
// preprocessing into ONE single-block kernel (LDS counters + LDS scan +
// LDS ranks; only qdesc/zlist/hdr written to global). cgp_main unchanged.

#define IN_DIM 1024
#define ROWS   4
#define NOBCAP 512

// ---- prep (1 block, 1024 thr): count -> scan -> pads/flags -> fill ----
__global__ __launch_bounds__(1024) void prep_kernel(
    const int* __restrict__ r1, const int* __restrict__ r2,
    const int* __restrict__ ro, const float* __restrict__ cg,
    int nseg, int nob,
    uint2* __restrict__ qdesc, int* __restrict__ zlist, int* __restrict__ hdr)
{
    __shared__ int cntS[NOBCAP];
    __shared__ int qscan[NOBCAP];
    __shared__ int zscan[NOBCAP];
    __shared__ int qoffS[NOBCAP];
    __shared__ unsigned int flagS[NOBCAP];
    __shared__ int rankS[NOBCAP];

    const int t = threadIdx.x;

    for (int j = t; j < NOBCAP; j += 1024) { cntS[j] = 0; rankS[j] = 0; }
    __syncthreads();

    // count segments per output block (native LDS int atomics)
    for (int s = t; s < nseg; s += 1024)
        atomicAdd(&cntS[ro[s << 5] >> 5], 1);
    __syncthreads();

    // per-ob quad count + shared flag; Hillis-Steele inclusive scan
    if (t < NOBCAP) {
        const int c = (t < nob) ? cntS[t] : 0;
        qscan[t] = (t < nob) ? (((c > 0 ? c : 1) + 3) >> 2) : 0;
        zscan[t] = (t < nob && c > 4) ? 1 : 0;
    }
    __syncthreads();
    for (int d = 1; d < NOBCAP; d <<= 1) {
        int vq = 0, vz = 0;
        if (t < NOBCAP && t >= d) { vq = qscan[t - d]; vz = zscan[t - d]; }
        __syncthreads();
        if (t < NOBCAP) { qscan[t] += vq; zscan[t] += vz; }
        __syncthreads();
    }
    if (t < nob) {
        const int c  = cntS[t];
        const int q  = ((c > 0 ? c : 1) + 3) >> 2;
        const int qb = qscan[t] - q;                 // exclusive base
        qoffS[t] = qb;
        const int sh = (c > 4) ? 1 : 0;
        const unsigned int fl = sh ? 0u : 0x80000000u;   // bit31 = exclusive
        flagS[t] = fl;
        if (sh) zlist[zscan[t] - 1] = t;
        const unsigned int pd = ((unsigned int)t << 20) | fl;   // pad: a=b=0, cg=0
        for (int j = (qb << 2) + c; j < ((qb + q) << 2); ++j)
            qdesc[j] = make_uint2(pd, 0u);
    }
    if (t == 0) {
        const int tot    = qscan[nob - 1];
        const int totPad = (tot + 7) & ~7;           // pad quad count to 8
        for (int j = (tot << 2); j < (totPad << 2); ++j)
            qdesc[j] = make_uint2(0u, 0u);           // dummy: +0.0 via shared path
        hdr[0] = totPad;
        hdr[1] = zscan[nob - 1];                     // number of shared obs
    }
    __syncthreads();

    // fill real descriptors (LDS rank atomics; order within ob arbitrary)
    for (int s = t; s < nseg; s += 1024) {
        const int k  = s << 5;
        const int ob = ro[k] >> 5;
        const int slot = (qoffS[ob] << 2) + atomicAdd(&rankS[ob], 1);
        qdesc[slot] = make_uint2((unsigned int)r1[k] | ((unsigned int)r2[k] << 10)
                                 | ((unsigned int)ob << 20) | flagS[ob],
                                 __float_as_uint(cg[k]));
    }
}

// ---- main: block = 4 rows, 8 waves; wave-iteration = one quad (R12) ----
__global__ __launch_bounds__(512) void cgp_main(const float* __restrict__ x1,
    const float* __restrict__ x2, const uint2* __restrict__ qdesc,
    const int* __restrict__ zlist, const int* __restrict__ hdr,
    float* __restrict__ out, int out_dim)
{
    __shared__ float x1s[ROWS * IN_DIM];
    __shared__ float x2s[ROWS * IN_DIM];
    const int r0  = blockIdx.x * ROWS;
    const int tid = threadIdx.x;

    // stage 4 rows of each input (read-only afterwards)
    {
        const float4* p1 = reinterpret_cast<const float4*>(x1 + (size_t)r0 * IN_DIM);
        const float4* p2 = reinterpret_cast<const float4*>(x2 + (size_t)r0 * IN_DIM);
        float4* s1 = reinterpret_cast<float4*>(x1s);
        float4* s2 = reinterpret_cast<float4*>(x2s);
        for (int j = tid; j < (ROWS * IN_DIM) >> 2; j += 512) { s1[j] = p1[j]; s2[j] = p2[j]; }
    }
    // zero only the shared obs of our 4 rows (exclusive obs are pure stores)
    const int nz = hdr[1];
    for (int i = tid; i < (nz << 5); i += 512) {
        const int ob = zlist[i >> 5];
        const int ch = i & 31;
        float* p = out + (size_t)r0 * out_dim + (ob << 5) + ch;
        p[0] = 0.f; p[out_dim] = 0.f; p[2 * out_dim] = 0.f; p[3 * out_dim] = 0.f;
    }
    __syncthreads();

    const int w  = tid >> 6;            // wave 0..7
    const int ln = tid & 63;
    const int rr = ln >> 4;             // row 0..3
    const int tt = ln & 15;             // float2-channel 0..15
    const float* xs1 = x1s + rr * IN_DIM + (tt << 1);
    const float* xs2 = x2s + rr * IN_DIM + (tt << 1);
    float* orow = out + (size_t)(r0 + rr) * out_dim + (tt << 1);

    const int nquads = hdr[0];          // multiple of 8
    const int qpw    = nquads >> 3;     // quads per wave
    const uint2* qd  = qdesc + ((size_t)(w * qpw) << 2);

    #pragma unroll 2
    for (int i = 0; i < qpw; ++i, qd += 4) {
        const uint4 A  = *reinterpret_cast<const uint4*>(qd);      // descs 0,1
        const uint4 Bq = *reinterpret_cast<const uint4*>(qd + 2);  // descs 2,3
        float sx = 0.f, sy = 0.f;
        {
            const float c = __uint_as_float(A.y);
            const float2 u = *reinterpret_cast<const float2*>(xs1 + (A.x & 1023u));
            const float2 v = *reinterpret_cast<const float2*>(xs2 + ((A.x >> 10) & 1023u));
            sx = fmaf(c, u.x * v.x, sx); sy = fmaf(c, u.y * v.y, sy);
        }
        {
            const float c = __uint_as_float(A.w);
            const float2 u = *reinterpret_cast<const float2*>(xs1 + (A.z & 1023u));
            const float2 v = *reinterpret_cast<const float2*>(xs2 + ((A.z >> 10) & 1023u));
            sx = fmaf(c, u.x * v.x, sx); sy = fmaf(c, u.y * v.y, sy);
        }
        {
            const float c = __uint_as_float(Bq.y);
            const float2 u = *reinterpret_cast<const float2*>(xs1 + (Bq.x & 1023u));
            const float2 v = *reinterpret_cast<const float2*>(xs2 + ((Bq.x >> 10) & 1023u));
            sx = fmaf(c, u.x * v.x, sx); sy = fmaf(c, u.y * v.y, sy);
        }
        {
            const float c = __uint_as_float(Bq.w);
            const float2 u = *reinterpret_cast<const float2*>(xs1 + (Bq.z & 1023u));
            const float2 v = *reinterpret_cast<const float2*>(xs2 + ((Bq.z >> 10) & 1023u));
            sx = fmaf(c, u.x * v.x, sx); sy = fmaf(c, u.y * v.y, sy);
        }
        float* p = orow + (((A.x >> 20) & 511u) << 5);
        if (A.x >> 31) {                               // exclusive ob: plain store
            *reinterpret_cast<float2*>(p) = make_float2(sx, sy);
        } else {                                       // shared ob: native fadd
            unsafeAtomicAdd(p, sx);
            unsafeAtomicAdd(p + 1, sy);
        }
    }
}

extern "C" void kernel_launch(void* const* d_in, const int* in_sizes, int n_in,
                              void* d_out, int out_size, void* d_ws, size_t ws_size,
                              hipStream_t stream)
{
    const float* x1 = (const float*)d_in[0];
    const float* x2 = (const float*)d_in[1];
    const float* cg = (const float*)d_in[2];
    const int*   r1 = (const int*)d_in[3];
    const int*   r2 = (const int*)d_in[4];
    const int*   ro = (const int*)d_in[5];
    float* out = (float*)d_out;

    const int B       = in_sizes[0] / IN_DIM;   // 2048
    const int out_dim = out_size / B;           // 8960
    const int K       = in_sizes[2];
    const int nseg    = K >> 5;                 // ~580
    const int nob     = out_dim >> 5;           // 280
    const int qcap    = nob + (nseg >> 2) + 16; // quad capacity upper bound

    auto align16 = [](size_t v) { return (v + 15) & ~(size_t)15; };
    char* ws = (char*)d_ws;
    uint2* qdesc = (uint2*)ws;  ws += align16((size_t)qcap * 4 * sizeof(uint2));
    int*   zlist = (int*)ws;    ws += align16((size_t)NOBCAP * sizeof(int));
    int*   hdr   = (int*)ws;

    hipLaunchKernelGGL(prep_kernel, dim3(1), dim3(1024), 0, stream,
                       r1, r2, ro, cg, nseg, nob, qdesc, zlist, hdr);
    hipLaunchKernelGGL(cgp_main, dim3(B / ROWS), dim3(512), 0, stream,
                       x1, x2, qdesc, zlist, hdr, out, out_dim);
}

// Round 14
// 30.427 us; speedup vs baseline: 7.3387x; 1.0647x over previous
//
#include <hip/hip_runtime.h>

// CGP coupler, duo+quad packed form, single-dispatch preprocessing.
//
// Structure (validated R3-R13): runs of 32 entries = segments
//   out[:, 32*ob:32*ob+32] += cg * x1[:, a:a+32] * x2[:, b:b+32]
// nseg ~ 580, nob = 280, per-ob counts c in 1..7 (avg ~2), a,b 32-aligned.
//
// R13: quad-only padding (ceil(c/4)*4 slots) wastes ~50% of desc slots on
// the dominant c<=2 obs. R14 packs by count:
//   c<=2 (incl empty) -> 1 duo  (2 slots), exclusive float2 store
//   3<=c<=4           -> 1 quad (4 slots), exclusive store
//   c>=5              -> quads, shared: pre-zeroed + global fadd atomics
// Main keeps the proven fat-body shape: quad loop (R13 body) + duo-PAIR
// loop (same 4-desc body, two independent terminals).

#define IN_DIM 1024
#define ROWS   4
#define NOBCAP 512

// ---- prep (1 block): count -> 3 scans -> pads/zlist/hdr -> fill ----
__global__ __launch_bounds__(1024) void prep_kernel(
    const int* __restrict__ r1, const int* __restrict__ r2,
    const int* __restrict__ ro, const float* __restrict__ cg,
    int nseg, int nob,
    uint2* __restrict__ qdesc, uint2* __restrict__ ddesc,
    int* __restrict__ zlist, int* __restrict__ hdr)
{
    __shared__ int cntS[NOBCAP], qs[NOBCAP], dsc[NOBCAP], zs[NOBCAP];
    __shared__ int qoffS[NOBCAP], doffS[NOBCAP], rankS[NOBCAP];
    const int t = threadIdx.x;

    for (int j = t; j < NOBCAP; j += 1024) { cntS[j] = 0; rankS[j] = 0; }
    __syncthreads();

    for (int s = t; s < nseg; s += 1024)
        atomicAdd(&cntS[ro[s << 5] >> 5], 1);
    __syncthreads();

    if (t < NOBCAP) {
        const int c = (t < nob) ? cntS[t] : 0;
        const bool duo = (t < nob) && (c <= 2);          // incl empty obs
        qs[t]  = (t < nob && c >= 3) ? ((c + 3) >> 2) : 0;
        dsc[t] = duo ? 1 : 0;
        zs[t]  = (t < nob && c > 4) ? 1 : 0;
    }
    __syncthreads();
    for (int d = 1; d < NOBCAP; d <<= 1) {
        int vq = 0, vd = 0, vz = 0;
        if (t < NOBCAP && t >= d) { vq = qs[t-d]; vd = dsc[t-d]; vz = zs[t-d]; }
        __syncthreads();
        if (t < NOBCAP) { qs[t] += vq; dsc[t] += vd; zs[t] += vz; }
        __syncthreads();
    }

    if (t < nob) {
        const int c = cntS[t];
        if (c <= 2) {                                    // duo ob
            const int db = dsc[t] - 1;
            doffS[t] = db;
            const unsigned int pd = ((unsigned int)t << 20) | 0x80000000u;
            for (int j = (db << 1) + c; j < ((db + 1) << 1); ++j)
                ddesc[j] = make_uint2(pd, 0u);           // pad: cg=0
        } else {                                         // quad ob
            const int qn = (c + 3) >> 2;
            const int qb = qs[t] - qn;
            qoffS[t] = qb;
            const unsigned int fl = (c > 4) ? 0u : 0x80000000u;
            if (c > 4) zlist[zs[t] - 1] = t;
            const unsigned int pd = ((unsigned int)t << 20) | fl;
            for (int j = (qb << 2) + c; j < ((qb + qn) << 2); ++j)
                qdesc[j] = make_uint2(pd, 0u);
        }
    }
    if (t == 0) {
        const int nq = qs[nob-1], nd = dsc[nob-1];
        const int nqPad = (nq + 7)  & ~7;                // 8 quads (1/wave)
        const int ndPad = (nd + 15) & ~15;               // 16 duos (2/wave)
        for (int j = (nq << 2); j < (nqPad << 2); ++j)
            qdesc[j] = make_uint2(0u, 0u);               // shared +0.0 dummy
        for (int j = (nd << 1); j < (ndPad << 1); ++j)
            ddesc[j] = make_uint2(0u, 0u);               // shared +0.0 dummy
        hdr[0] = nqPad; hdr[1] = zs[nob-1]; hdr[2] = ndPad;
    }
    __syncthreads();

    for (int s = t; s < nseg; s += 1024) {
        const int k  = s << 5;
        const int ob = ro[k] >> 5;
        const int c  = cntS[ob];
        const int rk = atomicAdd(&rankS[ob], 1);
        const unsigned int fl = (c > 4) ? 0u : 0x80000000u;
        const uint2 v = make_uint2((unsigned int)r1[k] | ((unsigned int)r2[k] << 10)
                                   | ((unsigned int)ob << 20) | fl,
                                   __float_as_uint(cg[k]));
        if (c <= 2) ddesc[(doffS[ob] << 1) + rk] = v;
        else        qdesc[(qoffS[ob] << 2) + rk] = v;
    }
}

// ---- main: block = 4 rows, 8 waves; quad loop + duo-pair loop ----
__global__ __launch_bounds__(512) void cgp_main(const float* __restrict__ x1,
    const float* __restrict__ x2, const uint2* __restrict__ qdesc,
    const uint2* __restrict__ ddesc, const int* __restrict__ zlist,
    const int* __restrict__ hdr, float* __restrict__ out, int out_dim)
{
    __shared__ float x1s[ROWS * IN_DIM];
    __shared__ float x2s[ROWS * IN_DIM];
    const int r0  = blockIdx.x * ROWS;
    const int tid = threadIdx.x;

    {
        const float4* p1 = reinterpret_cast<const float4*>(x1 + (size_t)r0 * IN_DIM);
        const float4* p2 = reinterpret_cast<const float4*>(x2 + (size_t)r0 * IN_DIM);
        float4* s1 = reinterpret_cast<float4*>(x1s);
        float4* s2 = reinterpret_cast<float4*>(x2s);
        for (int j = tid; j < (ROWS * IN_DIM) >> 2; j += 512) { s1[j] = p1[j]; s2[j] = p2[j]; }
    }
    const int nz = hdr[1];
    for (int i = tid; i < (nz << 5); i += 512) {
        const int ob = zlist[i >> 5];
        const int ch = i & 31;
        float* p = out + (size_t)r0 * out_dim + (ob << 5) + ch;
        p[0] = 0.f; p[out_dim] = 0.f; p[2 * out_dim] = 0.f; p[3 * out_dim] = 0.f;
    }
    __syncthreads();

    const int w  = tid >> 6;            // wave 0..7
    const int ln = tid & 63;
    const int rr = ln >> 4;             // row 0..3
    const int tt = ln & 15;             // float2-channel 0..15
    const float* xs1 = x1s + rr * IN_DIM + (tt << 1);
    const float* xs2 = x2s + rr * IN_DIM + (tt << 1);
    float* orow = out + (size_t)(r0 + rr) * out_dim + (tt << 1);

    // ---- quad loop (R13 body, obs with c>=3) ----
    {
        const int qpw = hdr[0] >> 3;
        const uint2* qd = qdesc + ((size_t)(w * qpw) << 2);
        #pragma unroll 2
        for (int i = 0; i < qpw; ++i, qd += 4) {
            const uint4 A  = *reinterpret_cast<const uint4*>(qd);
            const uint4 Bq = *reinterpret_cast<const uint4*>(qd + 2);
            float sx = 0.f, sy = 0.f;
            {
                const float c = __uint_as_float(A.y);
                const float2 u = *reinterpret_cast<const float2*>(xs1 + (A.x & 1023u));
                const float2 v = *reinterpret_cast<const float2*>(xs2 + ((A.x >> 10) & 1023u));
                sx = fmaf(c, u.x * v.x, sx); sy = fmaf(c, u.y * v.y, sy);
            }
            {
                const float c = __uint_as_float(A.w);
                const float2 u = *reinterpret_cast<const float2*>(xs1 + (A.z & 1023u));
                const float2 v = *reinterpret_cast<const float2*>(xs2 + ((A.z >> 10) & 1023u));
                sx = fmaf(c, u.x * v.x, sx); sy = fmaf(c, u.y * v.y, sy);
            }
            {
                const float c = __uint_as_float(Bq.y);
                const float2 u = *reinterpret_cast<const float2*>(xs1 + (Bq.x & 1023u));
                const float2 v = *reinterpret_cast<const float2*>(xs2 + ((Bq.x >> 10) & 1023u));
                sx = fmaf(c, u.x * v.x, sx); sy = fmaf(c, u.y * v.y, sy);
            }
            {
                const float c = __uint_as_float(Bq.w);
                const float2 u = *reinterpret_cast<const float2*>(xs1 + (Bq.z & 1023u));
                const float2 v = *reinterpret_cast<const float2*>(xs2 + ((Bq.z >> 10) & 1023u));
                sx = fmaf(c, u.x * v.x, sx); sy = fmaf(c, u.y * v.y, sy);
            }
            float* p = orow + (((A.x >> 20) & 511u) << 5);
            if (A.x >> 31) {
                *reinterpret_cast<float2*>(p) = make_float2(sx, sy);
            } else {
                unsafeAtomicAdd(p, sx);
                unsafeAtomicAdd(p + 1, sy);
            }
        }
    }

    // ---- duo-pair loop (obs with c<=2; two independent terminals) ----
    {
        const int ppw = (hdr[2] >> 1) >> 3;     // duo-pairs per wave
        const uint2* dd = ddesc + ((size_t)(w * ppw) << 2);
        #pragma unroll 2
        for (int i = 0; i < ppw; ++i, dd += 4) {
            const uint4 A  = *reinterpret_cast<const uint4*>(dd);      // duo 0
            const uint4 Bq = *reinterpret_cast<const uint4*>(dd + 2);  // duo 1
            float s0x = 0.f, s0y = 0.f, s1x = 0.f, s1y = 0.f;
            {
                const float c = __uint_as_float(A.y);
                const float2 u = *reinterpret_cast<const float2*>(xs1 + (A.x & 1023u));
                const float2 v = *reinterpret_cast<const float2*>(xs2 + ((A.x >> 10) & 1023u));
                s0x = fmaf(c, u.x * v.x, s0x); s0y = fmaf(c, u.y * v.y, s0y);
            }
            {
                const float c = __uint_as_float(A.w);
                const float2 u = *reinterpret_cast<const float2*>(xs1 + (A.z & 1023u));
                const float2 v = *reinterpret_cast<const float2*>(xs2 + ((A.z >> 10) & 1023u));
                s0x = fmaf(c, u.x * v.x, s0x); s0y = fmaf(c, u.y * v.y, s0y);
            }
            {
                const float c = __uint_as_float(Bq.y);
                const float2 u = *reinterpret_cast<const float2*>(xs1 + (Bq.x & 1023u));
                const float2 v = *reinterpret_cast<const float2*>(xs2 + ((Bq.x >> 10) & 1023u));
                s1x = fmaf(c, u.x * v.x, s1x); s1y = fmaf(c, u.y * v.y, s1y);
            }
            {
                const float c = __uint_as_float(Bq.w);
                const float2 u = *reinterpret_cast<const float2*>(xs1 + (Bq.z & 1023u));
                const float2 v = *reinterpret_cast<const float2*>(xs2 + ((Bq.z >> 10) & 1023u));
                s1x = fmaf(c, u.x * v.x, s1x); s1y = fmaf(c, u.y * v.y, s1y);
            }
            float* p0 = orow + (((A.x >> 20) & 511u) << 5);
            if (A.x >> 31) {
                *reinterpret_cast<float2*>(p0) = make_float2(s0x, s0y);
            } else {
                unsafeAtomicAdd(p0, s0x);
                unsafeAtomicAdd(p0 + 1, s0y);
            }
            float* p1 = orow + (((Bq.x >> 20) & 511u) << 5);
            if (Bq.x >> 31) {
                *reinterpret_cast<float2*>(p1) = make_float2(s1x, s1y);
            } else {
                unsafeAtomicAdd(p1, s1x);
                unsafeAtomicAdd(p1 + 1, s1y);
            }
        }
    }
}

extern "C" void kernel_launch(void* const* d_in, const int* in_sizes, int n_in,
                              void* d_out, int out_size, void* d_ws, size_t ws_size,
                              hipStream_t stream)
{
    const float* x1 = (const float*)d_in[0];
    const float* x2 = (const float*)d_in[1];
    const float* cg = (const float*)d_in[2];
    const int*   r1 = (const int*)d_in[3];
    const int*   r2 = (const int*)d_in[4];
    const int*   ro = (const int*)d_in[5];
    float* out = (float*)d_out;

    const int B       = in_sizes[0] / IN_DIM;   // 2048
    const int out_dim = out_size / B;           // 8960
    const int K       = in_sizes[2];
    const int nseg    = K >> 5;                 // ~580
    const int nob     = out_dim >> 5;           // 280
    const int qcap    = nob + (nseg >> 2) + 16; // quad capacity upper bound
    const int dcap    = nob + 32;               // duo capacity upper bound

    auto align16 = [](size_t v) { return (v + 15) & ~(size_t)15; };
    char* ws = (char*)d_ws;
    uint2* qdesc = (uint2*)ws;  ws += align16((size_t)qcap * 4 * sizeof(uint2));
    uint2* ddesc = (uint2*)ws;  ws += align16((size_t)dcap * 2 * sizeof(uint2));
    int*   zlist = (int*)ws;    ws += align16((size_t)NOBCAP * sizeof(int));
    int*   hdr   = (int*)ws;

    hipLaunchKernelGGL(prep_kernel, dim3(1), dim3(1024), 0, stream,
                       r1, r2, ro, cg, nseg, nob, qdesc, ddesc, zlist, hdr);
    hipLaunchKernelGGL(cgp_main, dim3(B / ROWS), dim3(512), 0, stream,
                       x1, x2, qdesc, ddesc, zlist, hdr, out, out_dim);
}

// Round 15
// 28.735 us; speedup vs baseline: 7.7707x; 1.0589x over previous
//
#include <hip/hip_runtime.h>

// CGP coupler, duo+quad packed, b128 8-row geometry, shuffle-scan prep.
//
// Structure (validated R3-R14): runs of 32 entries = segments
//   out[:, 32*ob:32*ob+32] += cg * x1[:, a:a+32] * x2[:, b:b+32]
// nseg ~ 580, nob = 280, per-ob counts c in 1..7 (avg ~2), a,b 32-aligned.
//
// R14 -> R15: (1) 8 rows/block with float4 lanes: each desc = 2 ds_read_b128
// covering 8 rows (halves DS instr count vs b64/4-row); (2) prep scan via
// packed wave-shuffle (3 barriers instead of 18); (3) tail-pad descriptors
// carry ob=511 and terminals skip them (kills the atomic-vs-store race on
// ob0 that R13/14 survived only by timing).

#define IN_DIM  1024
#define ROWS    8
#define NOBCAP  512
#define SKIP_OB 511u

// ---- prep (1 block, 1024 thr): count -> packed shuffle scan -> fill ----
__global__ __launch_bounds__(1024) void prep_kernel(
    const int* __restrict__ r1, const int* __restrict__ r2,
    const int* __restrict__ ro, const float* __restrict__ cg,
    int nseg, int nob,
    uint2* __restrict__ qdesc, uint2* __restrict__ ddesc,
    int* __restrict__ zlist, int* __restrict__ hdr)
{
    __shared__ int cntS[NOBCAP], rankS[NOBCAP];
    __shared__ int qoffS[NOBCAP], doffS[NOBCAP];
    __shared__ int wsum[8], woff[8];
    const int t = threadIdx.x;

    if (t < NOBCAP) { cntS[t] = 0; rankS[t] = 0; }
    __syncthreads();

    for (int s = t; s < nseg; s += 1024)
        atomicAdd(&cntS[ro[s << 5] >> 5], 1);
    __syncthreads();

    // packed per-ob value: q(quads)<<20 | d(is-duo)<<10 | z(is-shared);
    // every field's total stays < 1024 -> no inter-field carry.
    int c = 0;
    unsigned int pv = 0;
    if (t < NOBCAP) {
        c = (t < nob) ? cntS[t] : 0;
        const int q  = (t < nob && c >= 3) ? ((c + 3) >> 2) : 0;
        const int df = (t < nob && c <= 2) ? 1 : 0;
        const int zf = (t < nob && c > 4) ? 1 : 0;
        pv = ((unsigned int)q << 20) | ((unsigned int)df << 10) | (unsigned int)zf;
    }
    const int lane = t & 63;
    const int wid  = t >> 6;
    #pragma unroll
    for (int off = 1; off < 64; off <<= 1) {
        const unsigned int n = __shfl_up(pv, off, 64);
        if (lane >= off) pv += n;
    }
    if (t < NOBCAP && lane == 63) wsum[wid] = (int)pv;
    __syncthreads();
    if (t < 8) {
        unsigned int v = (unsigned int)wsum[t];
        const unsigned int self = v;
        #pragma unroll
        for (int off = 1; off < 8; off <<= 1) {
            const unsigned int n = __shfl_up(v, off, 64);
            if (t >= off) v += n;
        }
        woff[t] = (int)(v - self);               // exclusive wave offset
    }
    __syncthreads();

    if (t < NOBCAP) {
        const unsigned int incl = pv + (unsigned int)woff[wid];
        const int qi = (incl >> 20) & 1023;
        const int di = (incl >> 10) & 1023;
        const int zi = incl & 1023;
        if (t < nob) {
            if (c <= 2) {                                   // duo ob (incl empty)
                const int db = di - 1;
                doffS[t] = db;
                const unsigned int pd = ((unsigned int)t << 20) | 0x80000000u;
                for (int j = (db << 1) + c; j < ((db + 1) << 1); ++j)
                    ddesc[j] = make_uint2(pd, 0u);          // pad: cg=0
            } else {                                        // quad ob
                const int qn = (c + 3) >> 2;
                const int qb = qi - qn;
                qoffS[t] = qb;
                const unsigned int fl = (c > 4) ? 0u : 0x80000000u;
                if (c > 4) zlist[zi - 1] = t;
                const unsigned int pd = ((unsigned int)t << 20) | fl;
                for (int j = (qb << 2) + c; j < ((qb + qn) << 2); ++j)
                    qdesc[j] = make_uint2(pd, 0u);
            }
        }
        if (t == NOBCAP - 1) {                              // totals live here
            const int nq = qi, nd = di;
            const int nqPad = (nq + 15) & ~15;              // 16 quads (1/wave)
            const int ndPad = (nd + 31) & ~31;              // 32 duos (1 pair/wave)
            const uint2 dummy = make_uint2(SKIP_OB << 20, 0u);  // terminal skipped
            for (int j = (nq << 2); j < (nqPad << 2); ++j) qdesc[j] = dummy;
            for (int j = (nd << 1); j < (ndPad << 1); ++j) ddesc[j] = dummy;
            hdr[0] = nqPad; hdr[1] = zi; hdr[2] = ndPad;
        }
    }
    __syncthreads();

    for (int s = t; s < nseg; s += 1024) {
        const int k  = s << 5;
        const int ob = ro[k] >> 5;
        const int cc = cntS[ob];
        const int rk = atomicAdd(&rankS[ob], 1);
        const unsigned int fl = (cc > 4) ? 0u : 0x80000000u;
        const uint2 v = make_uint2((unsigned int)r1[k] | ((unsigned int)r2[k] << 10)
                                   | ((unsigned int)ob << 20) | fl,
                                   __float_as_uint(cg[k]));
        if (cc <= 2) ddesc[(doffS[ob] << 1) + rk] = v;
        else         qdesc[(qoffS[ob] << 2) + rk] = v;
    }
}

__device__ __forceinline__ void accum4(float4& acc, unsigned int dx, unsigned int dc,
                                       const float* xs1, const float* xs2)
{
    const float  c = __uint_as_float(dc);
    const float4 u = *reinterpret_cast<const float4*>(xs1 + (dx & 1023u));
    const float4 v = *reinterpret_cast<const float4*>(xs2 + ((dx >> 10) & 1023u));
    acc.x = fmaf(c, u.x * v.x, acc.x);
    acc.y = fmaf(c, u.y * v.y, acc.y);
    acc.z = fmaf(c, u.z * v.z, acc.z);
    acc.w = fmaf(c, u.w * v.w, acc.w);
}

__device__ __forceinline__ void terminal(float* orow, unsigned int hx, float4 acc,
                                         int out_dim)
{
    const int ob = (int)((hx >> 20) & 511u);
    if (ob == (int)SKIP_OB) return;                  // tail pad: no output
    float* p = orow + (ob << 5);
    if (hx >> 31) {
        *reinterpret_cast<float4*>(p) = acc;         // exclusive: plain store
    } else {                                         // shared: native fadd
        unsafeAtomicAdd(p,     acc.x);
        unsafeAtomicAdd(p + 1, acc.y);
        unsafeAtomicAdd(p + 2, acc.z);
        unsafeAtomicAdd(p + 3, acc.w);
    }
}

// ---- main: block = 8 rows, 16 waves; lane = row(3b) x float4-group(3b) ----
__global__ __launch_bounds__(1024) void cgp_main(const float* __restrict__ x1,
    const float* __restrict__ x2, const uint2* __restrict__ qdesc,
    const uint2* __restrict__ ddesc, const int* __restrict__ zlist,
    const int* __restrict__ hdr, float* __restrict__ out, int out_dim)
{
    __shared__ float x1s[ROWS * IN_DIM];             // 32 KB
    __shared__ float x2s[ROWS * IN_DIM];             // 32 KB
    const int r0  = blockIdx.x * ROWS;
    const int tid = threadIdx.x;

    {
        const float4* p1 = reinterpret_cast<const float4*>(x1 + (size_t)r0 * IN_DIM);
        const float4* p2 = reinterpret_cast<const float4*>(x2 + (size_t)r0 * IN_DIM);
        float4* s1 = reinterpret_cast<float4*>(x1s);
        float4* s2 = reinterpret_cast<float4*>(x2s);
        #pragma unroll
        for (int j = tid; j < (ROWS * IN_DIM) >> 2; j += 1024) { s1[j] = p1[j]; s2[j] = p2[j]; }
    }
    const int nz = hdr[1];
    for (int i = tid; i < (nz << 5); i += 1024) {    // pre-zero shared obs
        const int ob = zlist[i >> 5];
        const int ch = i & 31;
        float* p = out + (size_t)r0 * out_dim + (ob << 5) + ch;
        #pragma unroll
        for (int j = 0; j < ROWS; ++j) p[j * out_dim] = 0.f;
    }
    __syncthreads();

    const int w  = tid >> 6;                         // wave 0..15
    const int ln = tid & 63;
    const int rr = ln >> 3;                          // row 0..7
    const int tt = ln & 7;                           // float4-channel group
    const float* xs1 = x1s + rr * IN_DIM + (tt << 2);
    const float* xs2 = x2s + rr * IN_DIM + (tt << 2);
    float* orow = out + (size_t)(r0 + rr) * out_dim + (tt << 2);

    // ---- quad loop (obs with c>=3) ----
    {
        const int qpw = hdr[0] >> 4;                 // quads per wave
        const uint2* qd = qdesc + ((size_t)(w * qpw) << 2);
        #pragma unroll 2
        for (int i = 0; i < qpw; ++i, qd += 4) {
            const uint4 A  = *reinterpret_cast<const uint4*>(qd);
            const uint4 Bq = *reinterpret_cast<const uint4*>(qd + 2);
            float4 acc = make_float4(0.f, 0.f, 0.f, 0.f);
            accum4(acc, A.x,  A.y,  xs1, xs2);
            accum4(acc, A.z,  A.w,  xs1, xs2);
            accum4(acc, Bq.x, Bq.y, xs1, xs2);
            accum4(acc, Bq.z, Bq.w, xs1, xs2);
            terminal(orow, A.x, acc, out_dim);
        }
    }

    // ---- duo-pair loop (obs with c<=2; two independent terminals) ----
    {
        const int ppw = hdr[2] >> 5;                 // duo-pairs per wave
        const uint2* dd = ddesc + ((size_t)(w * ppw) << 2);
        #pragma unroll 2
        for (int i = 0; i < ppw; ++i, dd += 4) {
            const uint4 A  = *reinterpret_cast<const uint4*>(dd);
            const uint4 Bq = *reinterpret_cast<const uint4*>(dd + 2);
            float4 a0 = make_float4(0.f, 0.f, 0.f, 0.f);
            float4 a1 = make_float4(0.f, 0.f, 0.f, 0.f);
            accum4(a0, A.x,  A.y,  xs1, xs2);
            accum4(a0, A.z,  A.w,  xs1, xs2);
            accum4(a1, Bq.x, Bq.y, xs1, xs2);
            accum4(a1, Bq.z, Bq.w, xs1, xs2);
            terminal(orow, A.x,  a0, out_dim);
            terminal(orow, Bq.x, a1, out_dim);
        }
    }
}

extern "C" void kernel_launch(void* const* d_in, const int* in_sizes, int n_in,
                              void* d_out, int out_size, void* d_ws, size_t ws_size,
                              hipStream_t stream)
{
    const float* x1 = (const float*)d_in[0];
    const float* x2 = (const float*)d_in[1];
    const float* cg = (const float*)d_in[2];
    const int*   r1 = (const int*)d_in[3];
    const int*   r2 = (const int*)d_in[4];
    const int*   ro = (const int*)d_in[5];
    float* out = (float*)d_out;

    const int B       = in_sizes[0] / IN_DIM;   // 2048
    const int out_dim = out_size / B;           // 8960
    const int K       = in_sizes[2];
    const int nseg    = K >> 5;                 // ~580
    const int nob     = out_dim >> 5;           // 280
    const int qcap    = nob + (nseg >> 2) + 32; // quad capacity upper bound
    const int dcap    = nob + 48;               // duo capacity upper bound

    auto align16 = [](size_t v) { return (v + 15) & ~(size_t)15; };
    char* ws = (char*)d_ws;
    uint2* qdesc = (uint2*)ws;  ws += align16((size_t)qcap * 4 * sizeof(uint2));
    uint2* ddesc = (uint2*)ws;  ws += align16((size_t)dcap * 2 * sizeof(uint2));
    int*   zlist = (int*)ws;    ws += align16((size_t)NOBCAP * sizeof(int));
    int*   hdr   = (int*)ws;

    hipLaunchKernelGGL(prep_kernel, dim3(1), dim3(1024), 0, stream,
                       r1, r2, ro, cg, nseg, nob, qdesc, ddesc, zlist, hdr);
    hipLaunchKernelGGL(cgp_main, dim3(B / ROWS), dim3(1024), 0, stream,
                       x1, x2, qdesc, ddesc, zlist, hdr, out, out_dim);
}